// Round 9
// baseline (175.891 us; speedup 1.0000x reference)
//
#include <hip/hip_runtime.h>
#include <math.h>

constexpr int L_ = 2048, D_ = 128, H_ = 16;
constexpr int T_ = 8192;
constexpr int LDX = T_;              // col-major activations act[chan][token]

// ---- static device globals ----
__device__ float g_h   [D_ * T_];           // conv out, col-major
__device__ float g_qkv [3 * D_ * T_];       // col-major [384][8192]
__device__ float g_ctx [D_ * T_];
__device__ float g_Wf1T[D_ * D_];           // fused (W1*Wo)^T  [d][f]
__device__ float g_WfcT[D_ * D_];           // fused (Wfc*W2)^T [f][o], o>=80 zero
__device__ float g_bf1 [D_];
__device__ float g_bfc [D_];

// ---------------------------------------------------------------------------
// conv1x1 + ReLU + BN + inline posenc. Block = 32 tokens, 256 thr, TM4xTN4
// (tile 32 x 128). Transposing LDS stages for x and conv_w (pad 36 / 132:
// 16B-aligned rows, <=8-way one-time write conflicts). 256 blocks.
// ---------------------------------------------------------------------------
__global__ __launch_bounds__(256) void conv_kernel(
        const float* __restrict__ x, const float* __restrict__ conv_w,
        const float* __restrict__ conv_b,
        const float* __restrict__ bg, const float* __restrict__ bb,
        const float* __restrict__ brm, const float* __restrict__ brv) {
    __shared__ float Xs[80 * 36];
    __shared__ float Ws[80 * 132];
    int tid = threadIdx.x;
    int t0 = blockIdx.x * 32;

    for (int i = tid; i < 32 * 80; i += 256) {       // x [t][k] -> Xs[k][t]
        int t = i / 80, k = i - t * 80;
        Xs[k * 36 + t] = x[(size_t)t0 * 80 + i];
    }
    for (int i = tid; i < 128 * 80; i += 256) {      // conv_w [o][k] -> Ws[k][o]
        int o = i / 80, k = i - o * 80;
        Ws[k * 132 + o] = conv_w[i];
    }
    __syncthreads();

    int tc = tid & 31, tr = tid >> 5;                // 32 col-groups, 8 tok-groups
    float acc[4][4] = {};
#pragma unroll 4
    for (int k = 0; k < 80; k++) {
        float4 a = *(float4*)&Xs[k * 36 + tr * 4];
        float4 w = *(float4*)&Ws[k * 132 + tc * 4];
        float av[4] = {a.x, a.y, a.z, a.w};
        float wv[4] = {w.x, w.y, w.z, w.w};
#pragma unroll
        for (int i = 0; i < 4; i++)
#pragma unroll
            for (int jj = 0; jj < 4; jj++)
                acc[i][jj] = fmaf(av[i], wv[jj], acc[i][jj]);
    }

#pragma unroll
    for (int jj = 0; jj < 4; jj++) {
        int c = tc * 4 + jj;
        float bv = conv_b[c];
        float scale = bg[c] * rsqrtf(brv[c] + 1e-5f);
        float rm = brm[c], bbv = bb[c];
        float pfac = __expf((float)(c >> 1) * (-9.210340371976184f / 128.0f));
        float vs[4];
#pragma unroll
        for (int i = 0; i < 4; i++) {
            int t = t0 + tr * 4 + i;
            float v = fmaxf(acc[i][jj] + bv, 0.0f);
            v = (v - rm) * scale + bbv;
            float ang = (float)(t & 2047) * pfac;
            v += (c & 1) ? cosf(ang) : sinf(ang);
            vs[i] = v;
        }
        *(float4*)&g_h[(size_t)c * LDX + t0 + tr * 4] = *(float4*)vs;
    }
}

// ---------------------------------------------------------------------------
// qkv: K=128, tile 128 tokens x 64 cols, 256 thr, TM8xTN4, BK=64.
// W^T staged by transposing LDS write from row-major in_proj_w (pad 68).
// grid (64, 6) = 384 blocks.
// ---------------------------------------------------------------------------
__global__ __launch_bounds__(256) void qkv_kernel(
        const float* __restrict__ in_proj_w, const float* __restrict__ in_proj_b) {
    __shared__ float Xs[64 * 128];
    __shared__ float Ws[64 * 68];
    int tid = threadIdx.x;
    int t0 = blockIdx.x * 128;
    int cb = blockIdx.y * 64;
    int tc = tid & 15, tr = tid >> 4;

    float acc[8][4] = {};
    for (int kc = 0; kc < 128; kc += 64) {
        for (int i = tid; i < 64 * 32; i += 256) {   // h col-major -> Xs[k][t]
            int k = i >> 5, f = i & 31;
            *(float4*)&Xs[k * 128 + f * 4] =
                *(const float4*)&g_h[(size_t)(kc + k) * LDX + t0 + f * 4];
        }
        for (int i = tid; i < 64 * 64; i += 256) {   // W [o][k] -> Ws[k][o-local]
            int ol = i >> 6, kk = i & 63;
            Ws[kk * 68 + ol] = in_proj_w[(size_t)(cb + ol) * 128 + kc + kk];
        }
        __syncthreads();
#pragma unroll 4
        for (int k = 0; k < 64; k++) {
            float4 a0 = *(float4*)&Xs[k * 128 + tr * 8];
            float4 a1 = *(float4*)&Xs[k * 128 + tr * 8 + 4];
            float4 w  = *(float4*)&Ws[k * 68 + tc * 4];
            float av[8] = {a0.x, a0.y, a0.z, a0.w, a1.x, a1.y, a1.z, a1.w};
            float wv[4] = {w.x, w.y, w.z, w.w};
#pragma unroll
            for (int i = 0; i < 8; i++)
#pragma unroll
                for (int jj = 0; jj < 4; jj++)
                    acc[i][jj] = fmaf(av[i], wv[jj], acc[i][jj]);
        }
        __syncthreads();
    }

#pragma unroll
    for (int jj = 0; jj < 4; jj++) {
        int C = cb + tc * 4 + jj;
        float bv = in_proj_b[C];
        float vs[8];
#pragma unroll
        for (int i = 0; i < 8; i++) vs[i] = acc[i][jj] + bv;
        *(float4*)&g_qkv[(size_t)C * LDX + t0 + tr * 8]     = *(float4*)&vs[0];
        *(float4*)&g_qkv[(size_t)C * LDX + t0 + tr * 8 + 4] = *(float4*)&vs[4];
    }
}

// ---------------------------------------------------------------------------
// Attention (verbatim round-8 logic, proven) + weight-fold blocks.
// bid<256: attn, bh=bid>>2, tile=bid&3 (512-q tiles, 256 thr, 2 adjacent q).
// bid 256-319: fold1 (M1=W1*Wo, b1'); bid 320-383: fold2 (M2=Wfc*W2, b2').
// ---------------------------------------------------------------------------
__global__ __launch_bounds__(256) void attn_fold_kernel(
        const float* __restrict__ out_w,  const float* __restrict__ out_b,
        const float* __restrict__ ff_w1,  const float* __restrict__ ff_b1,
        const float* __restrict__ ff_w2,  const float* __restrict__ ff_b2,
        const float* __restrict__ fc_w,   const float* __restrict__ fc_b) {
    __shared__ float4 sm4[2592];                 // 41.5 KB
    int bid = blockIdx.x, tid = threadIdx.x;

    if (bid >= 256) {                            // ---- fold blocks ----
        float* rowbuf = (float*)sm4;             // [2][128]
        float* red = rowbuf + 256;               // [256]
        int sub = tid >> 7, k = tid & 127;
        if (bid < 320) {                         // fold1
            int f = (bid - 256) * 2 + sub;
            rowbuf[sub * 128 + k] = ff_w1[f * 128 + k];
            __syncthreads();
            float acc = 0.f;
#pragma unroll 8
            for (int o = 0; o < 128; o++)
                acc = fmaf(rowbuf[sub * 128 + o], out_w[o * 128 + k], acc);
            g_Wf1T[k * 128 + f] = acc;
            red[tid] = rowbuf[sub * 128 + k] * out_b[k];
            __syncthreads();
            for (int s = 64; s > 0; s >>= 1) {
                if (k < s) red[tid] += red[tid + s];
                __syncthreads();
            }
            if (k == 0) g_bf1[f] = red[sub * 128] + ff_b1[f];
        } else {                                 // fold2
            int o = (bid - 320) * 2 + sub;
            rowbuf[sub * 128 + k] = (o < 80) ? fc_w[o * 128 + k] : 0.f;
            __syncthreads();
            float acc = 0.f;
#pragma unroll 8
            for (int d = 0; d < 128; d++)
                acc = fmaf(rowbuf[sub * 128 + d], ff_w2[d * 128 + k], acc);
            g_WfcT[k * 128 + o] = acc;
            red[tid] = rowbuf[sub * 128 + k] * ff_b2[k];
            __syncthreads();
            for (int s = 64; s > 0; s >>= 1) {
                if (k < s) red[tid] += red[tid + s];
                __syncthreads();
            }
            if (k == 0) g_bfc[o] = (o < 80) ? (red[sub * 128] + fc_b[o]) : 0.f;
        }
        return;
    }

    // ---- attention ----
    float4* SK = sm4;                            // [2][2][324]
    float4* SV = sm4 + 1296;
    int bh = bid >> 2;
    int qb = (bid & 3) * 512;
    int b = bh >> 4, h = bh & 15;
    int tb = b * L_;
    int jbase = qb - 64;

    for (int c16 = 0; c16 < 16; c16++) {         // stage 16 ch x 641 slots
        int d = c16 & 7;
        int ch = ((c16 < 8) ? D_ : 2 * D_) + h * 8 + d;
        const float* src = g_qkv + (size_t)ch * LDX + tb;
        float4* base4 = ((c16 < 8) ? SK : SV) + (d >> 2) * 324;
        for (int s = tid; s < 641; s += 256) {
            int j = jbase + s;
            float v = ((unsigned)j < (unsigned)L_) ? src[j] : 0.f;
            ((float*)(base4 + (s & 1) * 648 + (s >> 1)))[d & 3] = v;
        }
    }
    __syncthreads();

    const float sc = 0.35355339059327373f;       // 1/sqrt(8)
    int q0 = qb + 2 * tid;
    float qa[8], qc[8];
#pragma unroll
    for (int d = 0; d < 8; d++) {
        qa[d] = g_qkv[(size_t)(h * 8 + d) * LDX + tb + q0] * sc;
        qc[d] = g_qkv[(size_t)(h * 8 + d) * LDX + tb + q0 + 1] * sc;
    }
    float l0 = 0.f, l1 = 0.f;
    float A0[8] = {}, A1[8] = {};
    int j00 = jbase + 2 * tid;

#pragma unroll 2
    for (int it = 0; it <= 129; it++) {
        int pp = it & 1, idx = tid + (it >> 1);
        float4 ka  = SK[pp * 648 + idx], kb2 = SK[pp * 648 + 324 + idx];
        float kv[8] = {ka.x, ka.y, ka.z, ka.w, kb2.x, kb2.y, kb2.z, kb2.w};
        float s0 = 0.f, s1 = 0.f;
#pragma unroll
        for (int d = 0; d < 8; d++) {
            s0 = fmaf(qa[d], kv[d], s0);
            s1 = fmaf(qc[d], kv[d], s1);
        }
        bool jv = (unsigned)(j00 + it) < (unsigned)L_;
        float w0 = (jv && it != 64 && it <= 128) ? __expf(s0) : 0.f;
        float w1 = (jv && it != 65 && it >= 1)  ? __expf(s1) : 0.f;
        l0 += w0; l1 += w1;
        float4 va  = SV[pp * 648 + idx], vb2 = SV[pp * 648 + 324 + idx];
        float vv[8] = {va.x, va.y, va.z, va.w, vb2.x, vb2.y, vb2.z, vb2.w};
#pragma unroll
        for (int d = 0; d < 8; d++) {
            A0[d] = fmaf(w0, vv[d], A0[d]);
            A1[d] = fmaf(w1, vv[d], A1[d]);
        }
    }
    float i0 = 1.f / l0, i1 = 1.f / l1;
    int base = tb + q0;
#pragma unroll
    for (int d = 0; d < 8; d++) {                // col-major ctx
        g_ctx[(size_t)(h * 8 + d) * LDX + base]     = A0[d] * i0;
        g_ctx[(size_t)(h * 8 + d) * LDX + base + 1] = A1[d] * i1;
    }
}

// ---------------------------------------------------------------------------
// Fused out_proj+ff1+ff2+fc tail. Block = 32 tokens, 256 thr, TM4xTN4.
// Phase A: f1 = relu(ctx*M1^T + b1') -> LDS F (pad 36, aligned b128 rows).
// Phase B: out = F*M2^T + b2' -> row-major [t][80]. 256 blocks.
// ---------------------------------------------------------------------------
__global__ __launch_bounds__(256) void f1fc_kernel(float* __restrict__ out) {
    __shared__ float Xs[128 * 32];
    __shared__ float Wsh[32 * 128];
    __shared__ float F[128 * 36];
    int tid = threadIdx.x;
    int t0 = blockIdx.x * 32;
    int tc = tid & 31, tr = tid >> 5;

    for (int i = tid; i < 128 * 8; i += 256) {   // ctx -> Xs[k][t]
        int k = i >> 3, f = i & 7;
        *(float4*)&Xs[k * 32 + f * 4] =
            *(const float4*)&g_ctx[(size_t)k * LDX + t0 + f * 4];
    }

    float acc[4][4] = {};
    for (int kc = 0; kc < 128; kc += 32) {
        for (int i = tid; i < 32 * 32; i += 256) {
            int k = i >> 5, f = i & 31;
            *(float4*)&Wsh[k * 128 + f * 4] =
                *(const float4*)&g_Wf1T[(size_t)(kc + k) * 128 + f * 4];
        }
        __syncthreads();
#pragma unroll 4
        for (int k = 0; k < 32; k++) {
            float4 a = *(float4*)&Xs[(kc + k) * 32 + tr * 4];
            float4 w = *(float4*)&Wsh[k * 128 + tc * 4];
            float av[4] = {a.x, a.y, a.z, a.w};
            float wv[4] = {w.x, w.y, w.z, w.w};
#pragma unroll
            for (int i = 0; i < 4; i++)
#pragma unroll
                for (int jj = 0; jj < 4; jj++)
                    acc[i][jj] = fmaf(av[i], wv[jj], acc[i][jj]);
        }
        __syncthreads();
    }
#pragma unroll
    for (int jj = 0; jj < 4; jj++) {             // relu + bias -> F[f][t]
        int c = tc * 4 + jj;
        float bv = g_bf1[c];
#pragma unroll
        for (int i = 0; i < 4; i++)
            F[c * 36 + tr * 4 + i] = fmaxf(acc[i][jj] + bv, 0.f);
    }
    __syncthreads();

    float acc2[4][4] = {};
    for (int kc = 0; kc < 128; kc += 32) {
        for (int i = tid; i < 32 * 32; i += 256) {
            int k = i >> 5, f = i & 31;
            *(float4*)&Wsh[k * 128 + f * 4] =
                *(const float4*)&g_WfcT[(size_t)(kc + k) * 128 + f * 4];
        }
        __syncthreads();
#pragma unroll 4
        for (int k = 0; k < 32; k++) {
            float4 a = *(float4*)&F[(kc + k) * 36 + tr * 4];
            float4 w = *(float4*)&Wsh[k * 128 + tc * 4];
            float av[4] = {a.x, a.y, a.z, a.w};
            float wv[4] = {w.x, w.y, w.z, w.w};
#pragma unroll
            for (int i = 0; i < 4; i++)
#pragma unroll
                for (int jj = 0; jj < 4; jj++)
                    acc2[i][jj] = fmaf(av[i], wv[jj], acc2[i][jj]);
        }
        __syncthreads();
    }
    if (tc < 20) {                               // cols 0..79 only
#pragma unroll
        for (int i = 0; i < 4; i++) {
            int t = t0 + tr * 4 + i;
            float vs[4];
#pragma unroll
            for (int jj = 0; jj < 4; jj++) vs[jj] = acc2[i][jj] + g_bfc[tc * 4 + jj];
            *(float4*)&out[(size_t)t * 80 + tc * 4] = *(float4*)vs;
        }
    }
}

// ---------------------------------------------------------------------------
extern "C" void kernel_launch(void* const* d_in, const int* in_sizes, int n_in,
                              void* d_out, int out_size, void* d_ws, size_t ws_size,
                              hipStream_t stream) {
    const float* x         = (const float*)d_in[0];
    const float* conv_w    = (const float*)d_in[1];
    const float* conv_b    = (const float*)d_in[2];
    const float* bn_g      = (const float*)d_in[3];
    const float* bn_b      = (const float*)d_in[4];
    const float* bn_rm     = (const float*)d_in[5];
    const float* bn_rv     = (const float*)d_in[6];
    const float* in_proj_w = (const float*)d_in[7];
    const float* in_proj_b = (const float*)d_in[8];
    const float* out_w     = (const float*)d_in[9];
    const float* out_b     = (const float*)d_in[10];
    const float* ff_w1     = (const float*)d_in[11];
    const float* ff_b1     = (const float*)d_in[12];
    const float* ff_w2     = (const float*)d_in[13];
    const float* ff_b2     = (const float*)d_in[14];
    const float* fc_w      = (const float*)d_in[15];
    const float* fc_b      = (const float*)d_in[16];

    conv_kernel<<<256, 256, 0, stream>>>(x, conv_w, conv_b, bn_g, bn_b, bn_rm, bn_rv);
    qkv_kernel<<<dim3(64, 6), 256, 0, stream>>>(in_proj_w, in_proj_b);
    attn_fold_kernel<<<384, 256, 0, stream>>>(out_w, out_b, ff_w1, ff_b1,
                                              ff_w2, ff_b2, fc_w, fc_b);
    f1fc_kernel<<<256, 256, 0, stream>>>((float*)d_out);
}